// Round 10
// baseline (6050.060 us; speedup 1.0000x reference)
//
#include <hip/hip_runtime.h>

// ---------------- problem constants ----------------
constexpr int N_ = 1024;   // ITEM_SIZE
constexpr int B_ = 64;     // BATCH
constexpr int T_ = 64;     // SEQ
constexpr int CAP = 128;   // max in-degree cap (mean ~33, max ~60)
constexpr size_t OUT0 = (size_t)B_ * T_ * N_;   // outs f32, then h f32

// ---------------- workspace layout (float offsets) — total ~13.9 MB ----------------
constexpr size_t WINTo  = 0;        // w_in^T  [j][i] 128*64 = 8192
constexpr size_t WOUTTo = 8192;     // w_out^T                 8192
constexpr size_t WIHTo  = 16384;    // w_ih^T  [j][g]  64*96 = 6144
constexpr size_t WHHo   = 22528;    // w_hh row-major          3072
constexpr size_t WFCo   = 25600;    // 32
constexpr size_t BINo   = 25632;    // 64
constexpr size_t BOUTo  = 25696;    // 64
constexpr size_t BIHo   = 25760;    // 96
constexpr size_t BHHo   = 25856;    // 96
constexpr size_t BFCo   = 25952;    // 16 (1 used)
constexpr size_t INAo   = 25968;    // 1024
constexpr size_t OUTAo  = 26992;    // 1024
constexpr size_t CCNTo  = 28016;    // 1024 int
constexpr size_t DTFo   = 29040;    // 16 (dtype flag int)
constexpr size_t IEMo   = 29056;    // item_emb f32 32768
constexpr size_t REMo   = 61824;    // resp_emb f32 65536
constexpr size_t SUMEMBo= 127360;   // sum item_emb over in-neighbors: 1024*32
constexpr size_t OMASKo = 160128;   // u64[1024][16] out-neighbor bitmask (32768 f-slots)
constexpr size_t CIDXo  = 192896;   // 1024*128 int (CSC col lists, ascending)
constexpr size_t GIBo   = 323968;   // gi cache bf16 [b][n][96] = 6,291,456 ushort (3,145,728 f-slots)
// end = 3,469,696 floats ≈ 13.9 MB

// ---------------- LDS layout (dynamic, float offsets) ----------------
constexpr int LDSF_H   = 0;         // h [1024][32] f32 = 32768
constexpr int LDSF_FEA = 32768;     // fea_stage [16][192] f32 = 3072
constexpr int LDSF_DL  = 35840;     // dlist 128 ints
constexpr int LDS_FLOATS = 35968;
constexpr int LDS_BYTES  = LDS_FLOATS * 4;   // 143,872 B -> 1 block/CU, 16 waves

// ---------------- helpers ----------------
__device__ __forceinline__ float bf2f(unsigned short u) {
    union { unsigned int i; float f; } x; x.i = ((unsigned int)u) << 16; return x.f;
}
__device__ __forceinline__ unsigned short f2bf(float f) {
    union { float f; unsigned int u; } x; x.f = f;
    unsigned int u = x.u;
    return (unsigned short)((u + 0x7fffu + ((u >> 16) & 1u)) >> 16);  // RNE
}
__device__ __forceinline__ float sigm(float x) { return 1.f / (1.f + __expf(-x)); }
__device__ __forceinline__ float tanhx(float x) {
    x = fminf(15.f, fmaxf(-15.f, x));
    float e = __expf(2.f * x);
    return (e - 1.f) / (e + 1.f);
}
__device__ __forceinline__ float ldg_any(const void* p, int i, int isbf) {
    return isbf ? bf2f(((const unsigned short*)p)[i]) : ((const float*)p)[i];
}

// ---------------- prep: detect input float dtype from adj bit patterns ----------------
__global__ void k_detect(const unsigned int* __restrict__ adjw, float* __restrict__ ws)
{
    __shared__ int f;
    if (threadIdx.x == 0) f = 0;
    __syncthreads();
    int local = 0;
    for (int i = threadIdx.x; i < 524288; i += blockDim.x) {
        unsigned int w = adjw[i];
        if ((w & 0xFFFFu) == 0x3F80u) local = 1;
    }
    if (local) atomicOr(&f, 1);
    __syncthreads();
    if (threadIdx.x == 0) ((int*)(ws + DTFo))[0] = f;
}

// ---------------- prep: convert/pack weights -> f32 ----------------
__global__ void k_convert(const void* __restrict__ w_in,  const void* __restrict__ b_in,
                          const void* __restrict__ w_out, const void* __restrict__ b_out,
                          const void* __restrict__ in_a,  const void* __restrict__ out_a,
                          const void* __restrict__ w_ih,  const void* __restrict__ w_hh,
                          const void* __restrict__ b_ih,  const void* __restrict__ b_hh,
                          const void* __restrict__ w_fc,  const void* __restrict__ b_fc,
                          const void* __restrict__ item_emb, const void* __restrict__ resp_emb,
                          float* __restrict__ ws)
{
    const int isbf = ((const int*)(ws + DTFo))[0];
    const int tg  = blockIdx.x * blockDim.x + threadIdx.x;
    const int tot = gridDim.x * blockDim.x;
    for (int f = tg; f < 8192; f += tot) {
        int i = f & 63, j = f >> 6;
        ws[WINTo + f]  = ldg_any(w_in , i * 128 + j, isbf);
        ws[WOUTTo + f] = ldg_any(w_out, i * 128 + j, isbf);
    }
    for (int f = tg; f < 6144; f += tot) {
        int g = f % 96, j = f / 96;
        ws[WIHTo + f] = ldg_any(w_ih, g * 64 + j, isbf);
    }
    for (int f = tg; f < 3072; f += tot) ws[WHHo + f] = ldg_any(w_hh, f, isbf);
    for (int f = tg; f < 32;   f += tot) ws[WFCo + f] = ldg_any(w_fc, f, isbf);
    for (int f = tg; f < 64;   f += tot) { ws[BINo + f] = ldg_any(b_in, f, isbf); ws[BOUTo + f] = ldg_any(b_out, f, isbf); }
    for (int f = tg; f < 96;   f += tot) { ws[BIHo + f] = ldg_any(b_ih, f, isbf); ws[BHHo + f] = ldg_any(b_hh, f, isbf); }
    if (tg == 0) ws[BFCo] = ldg_any(b_fc, 0, isbf);
    for (int f = tg; f < 1024; f += tot) { ws[INAo + f] = ldg_any(in_a, f, isbf); ws[OUTAo + f] = ldg_any(out_a, f, isbf); }
    for (int f = tg; f < 32768; f += tot) ws[IEMo + f] = ldg_any(item_emb, f, isbf);
    for (int f = tg; f < 65536; f += tot) ws[REMo + f] = ldg_any(resp_emb, f, isbf);
}

// ---------------- prep: build CSC adjacency (in-neighbor lists) ----------------
__global__ void k_csc(const void* __restrict__ adj, float* __restrict__ ws)
{
    const int isbf = ((const int*)(ws + DTFo))[0];
    const int v = blockIdx.x;
    const int lane = threadIdx.x;
    int* ccnt = (int*)(ws + CCNTo);
    int* cidx = (int*)(ws + CIDXo);
    int cnt = 0;
    for (int ch = 0; ch < 16; ++ch) {
        int row = ch * 64 + lane;
        bool nz;
        if (isbf) nz = (((const unsigned short*)adj)[row * 1024 + v] != 0);
        else      nz = (((const float*)adj)[row * 1024 + v] != 0.f);
        unsigned long long m = __ballot(nz);
        int pos = cnt + __popcll(m & ((1ull << lane) - 1ull));
        if (nz && pos < CAP) cidx[v * CAP + pos] = row;
        cnt += __popcll(m);
    }
    if (lane == 0) ccnt[v] = (cnt > CAP) ? CAP : cnt;
}

// ---------------- prep: out-neighbor bitmasks + static embedding sums ----------------
__global__ void k_emb(const void* __restrict__ adj, float* __restrict__ ws)
{
    const int isbf = ((const int*)(ws + DTFo))[0];
    const int v = blockIdx.x;
    const int lane = threadIdx.x;
    unsigned long long* om = (unsigned long long*)(ws + OMASKo);
    for (int w = 0; w < 16; ++w) {
        int col = w * 64 + lane;
        bool nz;
        if (isbf) nz = (((const unsigned short*)adj)[v * 1024 + col] != 0);
        else      nz = (((const float*)adj)[v * 1024 + col] != 0.f);
        unsigned long long m = __ballot(nz);
        if (lane == 0) om[v * 16 + w] = m;
    }
    const int cnt = ((const int*)(ws + CCNTo))[v];
    const int* cl = (const int*)(ws + CIDXo) + v * CAP;
    float acc = 0.f;
    for (int k = 0; k < cnt; ++k) {
        int u = cl[k];
        if (lane < 32) acc += ws[IEMo + u * 32 + lane];
    }
    if (lane < 32) ws[SUMEMBo + v * 32 + lane] = acc;
}

// ---------------- prep: gi(bf16) = b_ih (ws re-poisoned each launch) ----------------
__global__ void k_init(float* __restrict__ ws)
{
    const size_t tg  = (size_t)blockIdx.x * blockDim.x + threadIdx.x;
    const size_t tot = (size_t)gridDim.x * blockDim.x;
    const float* bih = ws + BIHo;
    unsigned short* gib = (unsigned short*)(ws + GIBo);
    for (size_t i = tg; i < 6291456u; i += tot) {
        int g = (int)(i % 96);            // [b][n][g]
        gib[i] = f2bf(bih[g]);
    }
}

// ---------------- main: 64 blocks (1/batch) x 1024 threads; ZERO cross-block sync ----------------
// h fp32 in LDS (128 KB). gi in global bf16 (same-CU L1-coherent across __syncthreads).
__global__ __launch_bounds__(1024, 1) void gkt_main(
    const int* __restrict__ item_ids, const int* __restrict__ responses,
    float* ws, float* __restrict__ out)
{
    extern __shared__ float smem[];
    float* h_lds = smem + LDSF_H;                 // [1024][32]
    float* fea_stage = smem + LDSF_FEA;           // [16][192]
    int* dlist = (int*)(smem + LDSF_DL);          // [128]

    const int tid  = threadIdx.x;
    const int lane = tid & 63;
    const int wave = tid >> 6;          // 0..15
    const int b    = blockIdx.x;        // batch
    const int s    = lane & 31;
    const int gsel = (lane >> 5) & 1;
    const int group= wave * 2 + gsel;   // 0..31, owns nodes [group*32, group*32+32)

    unsigned short* GIb = (unsigned short*)(ws + GIBo) + (size_t)b * 98304;  // [n][96] bf16
    const float* __restrict__ winT  = ws + WINTo;
    const float* __restrict__ woutT = ws + WOUTTo;
    const float* __restrict__ wihT  = ws + WIHTo;
    const float* __restrict__ whh   = ws + WHHo;
    const float* __restrict__ bin_f = ws + BINo;
    const float* __restrict__ bout_f= ws + BOUTo;
    const float* __restrict__ bih_f = ws + BIHo;
    const float* __restrict__ bhh_f = ws + BHHo;
    const float* __restrict__ ina_f = ws + INAo;
    const float* __restrict__ outa_f= ws + OUTAo;
    const float* __restrict__ iem   = ws + IEMo;
    const float* __restrict__ rem   = ws + REMo;
    const float* __restrict__ semb  = ws + SUMEMBo;
    const int* __restrict__ ccnt = (const int*)(ws + CCNTo);
    const int* __restrict__ cidx = (const int*)(ws + CIDXo);
    const unsigned long long* __restrict__ omk = (const unsigned long long*)(ws + OMASKo);

    // init h = 0
    for (int i = tid; i < 32768; i += 1024) h_lds[i] = 0.f;

    // register-stationary GRU recurrent weights for this lane's state index s
    float wr[32], wz[32], wn[32];
    #pragma unroll
    for (int j = 0; j < 32; ++j) {
        wr[j] = whh[s * 32 + j];
        wz[j] = whh[(32 + s) * 32 + j];
        wn[j] = whh[(64 + s) * 32 + j];
    }
    const float bhr = bhh_f[s], bhz = bhh_f[32 + s], bhn = bhh_f[64 + s];
    const float wfcs = ws[WFCo + s];
    const float bfc  = ws[BFCo];
    __syncthreads();

    for (int t = 0; t < T_; ++t) {
        const int item = item_ids[b * T_ + t];
        const int resp = responses[b * T_ + t];
        const int ndst = ccnt[item];
        if (tid < ndst) dlist[tid] = cidx[item * CAP + tid];
        __syncthreads();
        const float remv = (lane >= 32) ? rem[resp * 32 + (lane - 32)] : 0.f;

        // ---- phase A: one wave per dst node (i stride 16); full-wave h-agg ----
        float* fstage = fea_stage + wave * 192;
        for (int i = wave; i < ndst; i += 16) {
            const int v = dlist[i];
            const int cv = ccnt[v];
            const int* cl = cidx + v * CAP;
            // both 32-lane halves accumulate alternating k, fold via shfl_xor(32)
            float ph = 0.f;
            for (int k = gsel; k < cv; k += 2) {
                const int u = cl[k];
                ph += h_lds[u * 32 + s];
            }
            ph += __shfl_xor(ph, 32);
            float own, agg;
            if (lane < 32) {
                own = h_lds[v * 32 + lane];
                agg = ph;                                      // h half of src_fea
            } else {
                const int j = lane - 32;
                own = (v == item) ? remv : iem[v * 32 + j];
                const bool hasit = (omk[item * 16 + (v >> 6)] >> (v & 63)) & 1ull;
                agg = semb[v * 32 + j] + (hasit ? (remv - iem[item * 32 + j]) : 0.f);
            }
            fstage[lane]      = own;
            fstage[64 + lane] = agg;
            float ain = 0.f, aout = 0.f;
            const float4* f4p = (const float4*)fstage;
            #pragma unroll 8
            for (int c = 0; c < 32; ++c) {
                const float4 f = f4p[c];
                ain  += f.x * winT [(4*c+0)*64 + lane] + f.y * winT [(4*c+1)*64 + lane]
                      + f.z * winT [(4*c+2)*64 + lane] + f.w * winT [(4*c+3)*64 + lane];
                aout += f.x * woutT[(4*c+0)*64 + lane] + f.y * woutT[(4*c+1)*64 + lane]
                      + f.z * woutT[(4*c+2)*64 + lane] + f.w * woutT[(4*c+3)*64 + lane];
            }
            ain  += bin_f[lane];
            aout += bout_f[lane];
            const float dstv = outa_f[v] * aout + ina_f[v] * ain;
            fstage[128 + lane] = dstv;
            float g0 = bih_f[lane];
            float g1 = (lane < 32) ? bih_f[64 + lane] : 0.f;
            const float4* d4p = (const float4*)(fstage + 128);
            #pragma unroll 8
            for (int c = 0; c < 16; ++c) {
                const float4 dv = d4p[c];
                g0 += dv.x * wihT[(4*c+0)*96 + lane] + dv.y * wihT[(4*c+1)*96 + lane]
                    + dv.z * wihT[(4*c+2)*96 + lane] + dv.w * wihT[(4*c+3)*96 + lane];
                if (lane < 32) {
                    g1 += dv.x * wihT[(4*c+0)*96 + 64 + lane] + dv.y * wihT[(4*c+1)*96 + 64 + lane]
                        + dv.z * wihT[(4*c+2)*96 + 64 + lane] + dv.w * wihT[(4*c+3)*96 + 64 + lane];
                }
            }
            unsigned short* grow = GIb + (size_t)v * 96;
            grow[lane] = f2bf(g0);
            if (lane < 32) grow[64 + lane] = f2bf(g1);
        }
        __syncthreads();   // gi (global, same-CU write-through L1) + h reads done

        // ---- phase B: GRU; group owns 32 nodes; gi ring-1 prefetch from global ----
        {
            int nl = group * 32;
            const unsigned short* gp = GIb + (size_t)nl * 96;
            unsigned short cS = gp[s], c32 = gp[32 + s], c64 = gp[64 + s];
            for (int i = 0; i < 32; ++i, ++nl) {
                unsigned short nS = 0, n32 = 0, n64 = 0;
                if (i < 31) {
                    const unsigned short* gn = GIb + (size_t)(nl + 1) * 96;
                    nS = gn[s]; n32 = gn[32 + s]; n64 = gn[64 + s];
                }
                const float4* hrow = (const float4*)(h_lds + nl * 32);
                float4 ch[8];
                #pragma unroll
                for (int q = 0; q < 8; ++q) ch[q] = hrow[q];
                const float h_own = h_lds[nl * 32 + s];
                float ar = bhr, az = bhz, an = bhn;
                const float* hf = (const float*)ch;
                #pragma unroll
                for (int j = 0; j < 32; ++j) {
                    const float hv = hf[j];
                    ar += wr[j] * hv; az += wz[j] * hv; an += wn[j] * hv;
                }
                const float gir = bf2f(cS), giz = bf2f(c32), gin = bf2f(c64);
                const float rg = sigm(gir + ar);
                const float zg = sigm(giz + az);
                const float ng = tanhx(gin + rg * an);
                const float hv2 = (1.f - zg) * ng + zg * h_own;
                h_lds[nl * 32 + s] = hv2;
                float red = hv2 * wfcs;
                red += __shfl_xor(red, 16); red += __shfl_xor(red, 8);
                red += __shfl_xor(red, 4);  red += __shfl_xor(red, 2);
                red += __shfl_xor(red, 1);
                if (s == 0) out[(size_t)b * 65536 + (size_t)t * 1024 + nl] = sigm(red + bfc);
                if (t == T_ - 1) out[OUT0 + (size_t)b * 32768 + (size_t)nl * 32 + s] = hv2;
                cS = nS; c32 = n32; c64 = n64;
            }
        }
        __syncthreads();   // h writes visible before next step's phase A
    }
}

extern "C" void kernel_launch(void* const* d_in, const int* in_sizes, int n_in,
                              void* d_out, int out_size, void* d_ws, size_t ws_size,
                              hipStream_t stream)
{
    (void)in_sizes; (void)n_in; (void)out_size; (void)ws_size;
    const int* item_ids  = (const int*)d_in[0];
    const int* responses = (const int*)d_in[1];
    const void* adj      = d_in[2];
    const void* item_emb = d_in[3];
    const void* resp_emb = d_in[4];
    const void* w_in  = d_in[5];
    const void* b_in  = d_in[6];
    const void* w_out = d_in[7];
    const void* b_out = d_in[8];
    const void* in_a  = d_in[9];
    const void* out_a = d_in[10];
    const void* w_ih  = d_in[11];
    const void* w_hh  = d_in[12];
    const void* b_ih  = d_in[13];
    const void* b_hh  = d_in[14];
    const void* w_fc  = d_in[15];
    const void* b_fc  = d_in[16];
    float* ws = (float*)d_ws;
    float* out = (float*)d_out;

    (void)hipFuncSetAttribute((const void*)gkt_main,
                              hipFuncAttributeMaxDynamicSharedMemorySize, LDS_BYTES);

    k_detect<<<dim3(1), dim3(1024), 0, stream>>>((const unsigned int*)adj, ws);
    k_convert<<<dim3(64), dim3(256), 0, stream>>>(w_in, b_in, w_out, b_out, in_a, out_a,
                                                  w_ih, w_hh, b_ih, b_hh, w_fc, b_fc,
                                                  item_emb, resp_emb, ws);
    k_csc<<<dim3(1024), dim3(64), 0, stream>>>(adj, ws);
    k_emb<<<dim3(1024), dim3(64), 0, stream>>>(adj, ws);
    k_init<<<dim3(512), dim3(256), 0, stream>>>(ws);

    gkt_main<<<dim3(64), dim3(1024), LDS_BYTES, stream>>>(item_ids, responses, ws, out);
}